// Round 22
// baseline (174.909 us; speedup 1.0000x reference)
//
#include <hip/hip_runtime.h>

typedef unsigned short u16;
typedef unsigned int   u32;
typedef short bf8v  __attribute__((ext_vector_type(8)));   // 8 bf16 as shorts
typedef short s16x4 __attribute__((ext_vector_type(4)));
typedef float f32x4 __attribute__((ext_vector_type(4)));

#define DEV static __device__ __forceinline__
#define MBYTE (1u<<20)

// ---- bf16 helpers (RNE) ----
DEV u16 f2b(float f) {
    u32 u = __builtin_bit_cast(u32, f);
    u32 r = (u + 0x7fffu + ((u >> 16) & 1u)) >> 16;
    return (u16)r;
}
DEV float b2f(u16 s) { return __builtin_bit_cast(float, (u32)s << 16); }
DEV bf8v ld8(const u16* p) { return *reinterpret_cast<const bf8v*>(p); }

// load 8 consecutive elements as bf16, from f32 or bf16 source
DEV bf8v ldelems(const void* X, long idx, int f32f) {
    if (f32f) {
        const float* p = (const float*)X + idx;
        f32x4 a = *(const f32x4*)p;
        f32x4 b = *(const f32x4*)(p + 4);
        bf8v r;
        r[0] = (short)f2b(a[0]); r[1] = (short)f2b(a[1]);
        r[2] = (short)f2b(a[2]); r[3] = (short)f2b(a[3]);
        r[4] = (short)f2b(b[0]); r[5] = (short)f2b(b[1]);
        r[6] = (short)f2b(b[2]); r[7] = (short)f2b(b[3]);
        return r;
    }
    return ld8((const u16*)X + idx);
}
DEV float ldscalar(const void* X, long idx, int f32f) {
    return f32f ? ((const float*)X)[idx] : b2f(((const u16*)X)[idx]);
}

DEV f32x4 mfma_(bf8v a, bf8v b, f32x4 c) {
    return __builtin_amdgcn_mfma_f32_16x16x32_bf16(a, b, c, 0, 0, 0);
}

// global -> LDS direct (16B per lane). LDS dest = wave-uniform base + lane*16.
DEV void gload16(void* lds, const void* g) {
    __builtin_amdgcn_global_load_lds(
        (const __attribute__((address_space(1))) void*)g,
        (__attribute__((address_space(3))) void*)lds,
        16, 0, 0);
}

// ================= dtype sniff + relT build (one block) =================
__global__ __launch_bounds__(256) void sniffrelk(const u32* q, const u32* m,
                                                 const void* rel, u16* relT, int* flags) {
    __shared__ int c1s, c2s;
    int t = threadIdx.x;
    if (t == 0) { c1s = 0; c2s = 0; }
    __syncthreads();
    int c1 = 0, c2 = 0;
    for (int i = t; i < 1024; i += 256) {
        u32 u = q[i];
        int e = (int)((u >> 23) & 0xff);
        if (u == 0u || (e >= 118 && e <= 134)) c1++;
        if (m[i] > 1u) c2++;
    }
    atomicAdd(&c1s, c1);
    atomicAdd(&c2s, c2);
    __syncthreads();
    int f32f = (c1s > 512) ? 1 : 0;
    if (t == 0) { flags[0] = f32f; flags[1] = (c2s > 100) ? 1 : 0; }
    for (int i = t; i < 64 * 64; i += 256) {
        int d = i >> 6, r = i & 63;
        relT[i] = f32f ? f2b(((const float*)rel)[r * 64 + d]) : ((const u16*)rel)[r * 64 + d];
    }
}

// ======================= weight transpose (64x64 tiles), dual-dtype src =======================
__global__ __launch_bounds__(256) void tposek(const void* s0, const void* s1,
                                              const void* s2, const void* s3,
                                              u16* d0, u16* d1, u16* d2, u16* d3,
                                              const int* flags) {
    __shared__ u16 tile[64][65];
    int f32f = flags[0];
    int z = blockIdx.z;
    const void* src = z == 0 ? s0 : (z == 1 ? s1 : (z == 2 ? s2 : s3));
    u16*       dst = z == 0 ? d0 : (z == 1 ? d1 : (z == 2 ? d2 : d3));
    int t = threadIdx.x;
    int r0 = blockIdx.y * 64, c0 = blockIdx.x * 64;
#pragma unroll
    for (int i = 0; i < 16; ++i) {
        int u = i * 256 + t;
        int row = u >> 6, col = u & 63;
        long gi = (long)(r0 + row) * 1024 + c0 + col;
        tile[row][col] = f32f ? f2b(((const float*)src)[gi]) : ((const u16*)src)[gi];
    }
    __syncthreads();
#pragma unroll
    for (int i = 0; i < 8; ++i) {
        int u = i * 256 + t;
        int row = u >> 5, col = (u & 31) * 2;
        u32 v = (u32)tile[col][row] | ((u32)tile[col + 1][row] << 16);
        *(u32*)(dst + (long)(c0 + row) * 1024 + r0 + col) = v;
    }
}

// ======= 128x128 bf16 GEMM, BK=32, 8 waves, XCD-panel-mapped, 2-phase dbuf =======
// Per iter: issue stage(next) -> compute(cur) -> write A(next) -> ONE barrier.
// LDS XOR-swizzle (both sides): logical slot s of row r at physical slot s^((r>>1)&3).
// Blocks with blockIdx.x >= gemm_nwg run the attn-rescale path (piggyback on idle CUs).
// mode 0 scales Q by 0.125*log2(e): scores land in log2 domain -> attnk uses exp2.
__global__ __launch_bounds__(512) void gemm128(
    const void* x0, const void* x1, const void* x2,
    const u16* w0, const u16* w1, const u16* w2,
    const void* b0, const void* b1, const void* b2,
    void* c0, void* c1, void* c2, int mode_base,
    const int* flags, int a_use_flag, int gemm_nwg,
    void* dout, const u16* linv_g) {
    __shared__ __align__(16) u16 Al[2][128 * 32];
    __shared__ __align__(16) u16 Bl[2][128 * 32];

    int j = blockIdx.x;
    int t = threadIdx.x;
    int f32m = flags[0];

    if (j >= gemm_nwg) {                    // ---- piggybacked attn rescale ----
        int rb = j - gemm_nwg;              // 0..127, each covers 32768 elements
#pragma unroll
        for (int i = 0; i < 8; ++i) {       // 8 * 512 * 8 = 32768 elements
            long e0 = ((long)rb * 32768) + (long)(i * 512 + t) * 8;
            float inv = b2f(linv_g[e0 >> 10]);
            if (f32m) {
                float* a = (float*)dout + 4194304 + e0;
                f32x4 v0 = *(f32x4*)a, v1 = *(f32x4*)(a + 4);
#pragma unroll
                for (int r = 0; r < 4; ++r) { v0[r] *= inv; v1[r] *= inv; }
                *(f32x4*)a = v0; *(f32x4*)(a + 4) = v1;
            } else {
                u16* a = (u16*)dout + 4194304 + e0;
                bf8v v = *(bf8v*)a;
                bf8v o;
#pragma unroll
                for (int r = 0; r < 8; ++r) o[r] = (short)f2b(b2f((u16)v[r]) * inv);
                *(bf8v*)a = o;
            }
        }
        return;
    }

    int nwg = gemm_nwg;
    int ppx = nwg >> 6;                     // panels per XCD (12 for QKV, 4 for out)
    int xcd = j & 7, idx = j >> 3;
    int panel = xcd * ppx + (idx >> 3);
    int n0 = (idx & 7) * 128;
    int m0 = (panel & 31) * 128;
    int z  = panel >> 5;

    const void* X    = z == 0 ? x0 : (z == 1 ? x1 : x2);
    const u16*  BT   = z == 0 ? w0 : (z == 1 ? w1 : w2);
    const void* bias = z == 0 ? b0 : (z == 1 ? b1 : b2);
    void*       C    = z == 0 ? c0 : (z == 1 ? c1 : c2);
    int mode = mode_base + z;
    int f32a = a_use_flag ? f32m : 0;

    int w = t >> 6, l = t & 63;
    int lr = l & 15, lg = l >> 4;
    int wr = (w >> 1) * 32, wc = (w & 1) * 64;   // wave quadrant: 32 rows x 64 cols

    int rS = t >> 2;                        // staging row 0..127
    int sP = t & 3;                         // physical 16B slot
    int sL = sP ^ ((rS >> 1) & 3);          // logical slot fetched by this thread

    f32x4 acc[2][4];
    f32x4 zf = {0.f, 0.f, 0.f, 0.f};
#pragma unroll
    for (int mt = 0; mt < 2; ++mt)
#pragma unroll
        for (int nt = 0; nt < 4; ++nt) acc[mt][nt] = zf;

    // prologue: stage K-slice 0 into buffer 0
    gload16((char*)Bl[0] + w * 1024,
            (const char*)BT + (long)(n0 + rS) * 2048 + sL * 16);
    bf8v va0 = ldelems(X, (long)(m0 + rS) * 1024 + sL * 8, f32a);
    *(bf8v*)((char*)Al[0] + rS * 64 + sP * 16) = va0;
    __syncthreads();

    int cur = 0;
    for (int kk = 0; kk < 32; ++kk) {
        int nxt = cur ^ 1;
        bf8v va_n;
        if (kk < 31) {                      // issue next-slice loads BEFORE compute
            gload16((char*)Bl[nxt] + w * 1024,
                    (const char*)BT + (long)(n0 + rS) * 2048 + (long)(kk + 1) * 64 + sL * 16);
            va_n = ldelems(X, (long)(m0 + rS) * 1024 + (kk + 1) * 32 + sL * 8, f32a);
        }
        bf8v af[2], bfr[4];
#pragma unroll
        for (int mt = 0; mt < 2; ++mt) {
            int r = wr + mt * 16 + lr;
            af[mt] = *(const bf8v*)((const char*)Al[cur] + r * 64 + ((lg * 16) ^ (((r >> 1) & 3) << 4)));
        }
#pragma unroll
        for (int nt = 0; nt < 4; ++nt) {
            int r = wc + nt * 16 + lr;
            bfr[nt] = *(const bf8v*)((const char*)Bl[cur] + r * 64 + ((lg * 16) ^ (((r >> 1) & 3) << 4)));
        }
#pragma unroll
        for (int mt = 0; mt < 2; ++mt)
#pragma unroll
            for (int nt = 0; nt < 4; ++nt) acc[mt][nt] = mfma_(af[mt], bfr[nt], acc[mt][nt]);
        if (kk < 31) *(bf8v*)((char*)Al[nxt] + rS * 64 + sP * 16) = va_n;
        __syncthreads();                    // single barrier: drains B DMA + A write, frees cur
        cur = nxt;
    }

#pragma unroll
    for (int nt = 0; nt < 4; ++nt) {
        int col = n0 + wc + nt * 16 + lr;
        float bv = f32m ? ((const float*)bias)[col] : b2f(((const u16*)bias)[col]);
#pragma unroll
        for (int mt = 0; mt < 2; ++mt) {
#pragma unroll
            for (int r = 0; r < 4; ++r) {
                int m = m0 + wr + mt * 16 + lg * 4 + r;
                float v = acc[mt][nt][r] + bv;
                if (mode == 0) v *= 0.18033688f;   // 0.125 * log2(e): log2-domain scores
                if (mode <= 1) {
                    int bb = m >> 10, s = m & 1023, hh = col >> 6, dd = col & 63;
                    ((u16*)C)[(((bb << 4) + hh) * 1024 + s) * 64 + dd] = f2b(v);
                } else if (mode == 2) {
                    int bb = m >> 10, s = m & 1023, hh = col >> 6, dd = col & 63;
                    ((u16*)C)[(((bb << 4) + hh) * 64 + dd) * 1024 + s] = f2b(v);
                } else {
                    long idx2 = (long)m * 1024 + col;
                    if (f32m) ((float*)C)[idx2] = v; else ((u16*)C)[idx2] = f2b(v);
                }
            }
        }
    }
}

// ======================= fused relative attention (single pass, max-free, log2 domain) =======================
__global__ __launch_bounds__(256) void attnk(
    const u16* __restrict__ Qw, const u16* __restrict__ Kw, const u16* __restrict__ Vtw,
    const void* __restrict__ rel, const u16* __restrict__ relT,
    const void* __restrict__ mask,
    u16* __restrict__ ctx, void* __restrict__ dout, u16* __restrict__ linv_g,
    const int* __restrict__ flags) {
    __shared__ __align__(16) u16 Klds[2][32 * 64];   // [chunk][key][d] 128B rows, swizzled
    __shared__ __align__(16) u16 Vlds[2][64 * 32];   // [chunk][d][key] 64B rows, swizzled
    __shared__ u16 qrelB[64][64];                    // qrel[q][i], i=0..63 (i=64 in regs)
    __shared__ __align__(16) u16 P_lds[4][16][40];
    __shared__ __align__(16) u16 arel_lds[4][16][64];
    __shared__ float linv_lds[64];
    __shared__ float tlo_lds[64], thi_lds[64];
    __shared__ u16 maskB[1024];

    int f32f = flags[0], m8 = flags[1];
    float* attnF = (float*)dout + 4194304;
    u16*   attnB = (u16*)dout + 4194304;

    int t = threadIdx.x, w = t >> 6, l = t & 63;
    int lr = l & 15, lg = l >> 4;
    int id = blockIdx.x;
    int xcd = id & 7, j = id >> 3;
    int bh = xcd * 8 + (j & 7);
    int qb = j >> 3;
    int b = bh >> 4, h = bh & 15;
    int q0 = qb * 64;
    int qw0 = q0 + w * 16;
    const u16* Qh  = Qw  + (((b << 4) + h) << 16);
    const u16* Kh  = Kw  + (((b << 4) + h) << 16);
    const u16* Vth = Vtw + (((b << 4) + h) << 16);

    // ---- stage chunk 0 ----
    int rowK = w * 8 + (l >> 3);
    int scK  = 16 * ((l & 7) ^ ((l >> 3) & 7));
    int rowV = w * 16 + (l >> 2);
    int scV  = ((l & 3) * 16) ^ (((l >> 2) & 3) << 4);
    gload16((char*)&Klds[0][0] + w * 1024, (const char*)Kh + (long)rowK * 128 + scK);
    gload16((char*)&Vlds[0][0] + w * 1024, (const char*)Vth + (long)rowV * 2048 + scV);

    // ---- init LDS (mask, arel zero) ----
    for (int i = t; i < 1024; i += 256) {
        int mv = m8 ? (int)((const unsigned char*)mask)[(b << 10) + i]
                    : ((const int*)mask)[(b << 10) + i];
        maskB[i] = mv ? f2b(-1.0e18f) : 0;
    }
#pragma unroll
    for (int i = 0; i < 8; ++i) ((u32*)&arel_lds[0][0][0])[t + i * 256] = 0;

    int qg = q0 + w * 16 + lr;             // this lane's query row
    bf8v qf0 = ld8(Qh + qg * 64 + lg * 8);
    bf8v qf1 = ld8(Qh + qg * 64 + 32 + lg * 8);

    // qrel[q][i] = Qs[q]·rel[i]  via mfma(rel, Q); store i=0..63 bf16, i=64 via shfl
    // (Qs pre-scaled by log2(e): qrel is already in log2 domain)
    float lo_src = 0.f, hi_src = 0.f;
#pragma unroll
    for (int rt = 0; rt < 5; ++rt) {
        int rrow = rt * 16 + lr; if (rrow > 64) rrow = 64;
        f32x4 aq = {0.f, 0.f, 0.f, 0.f};
        aq = mfma_(ldelems(rel, rrow * 64 + lg * 8, f32f), qf0, aq);
        aq = mfma_(ldelems(rel, rrow * 64 + 32 + lg * 8, f32f), qf1, aq);
        if (rt < 4) {
#pragma unroll
            for (int r = 0; r < 4; ++r) qrelB[w * 16 + lr][rt * 16 + lg * 4 + r] = f2b(aq[r]);
            if (rt == 0) lo_src = aq[0];
        } else {
            hi_src = aq[0];
        }
    }
    float qrel_lo = __shfl(lo_src, lr);    // lane (lr, lg=0) holds qrel[lr][0]
    float qrel_hi = __shfl(hi_src, lr);
    const u16* qrow_rel = qrelB[w * 16 + lr];

    __syncthreads();                       // stage0 + LDS init complete

    float l_run = 0.f, tlo = 0.f, thi = 0.f;
    f32x4 acc[4];
#pragma unroll
    for (int dt = 0; dt < 4; ++dt) acc[dt] = f32x4{0.f, 0.f, 0.f, 0.f};

    for (int kc = 0; kc < 32; ++kc) {
        int cur = kc & 1;
        int k0 = kc * 32;
        if (kc < 31) {                     // stage next chunk
            int k1 = k0 + 32;
            gload16((char*)&Klds[cur ^ 1][0] + w * 1024,
                    (const char*)Kh + (long)(k1 + rowK) * 128 + scK);
            gload16((char*)&Vlds[cur ^ 1][0] + w * 1024,
                    (const char*)Vth + (long)rowV * 2048 + k1 * 2 + scV);
        }
        const char* KB = (const char*)&Klds[cur][0];
        const char* VB = (const char*)&Vlds[cur][0];

        // K fragments from LDS (swizzled)
        bf8v kf0 = *(const bf8v*)(KB + lr * 128 + ((lg * 16) ^ ((lr & 7) << 4)));
        bf8v kf1 = *(const bf8v*)(KB + lr * 128 + ((64 + lg * 16) ^ ((lr & 7) << 4)));
        bf8v kf2 = *(const bf8v*)(KB + (16 + lr) * 128 + ((lg * 16) ^ ((lr & 7) << 4)));
        bf8v kf3 = *(const bf8v*)(KB + (16 + lr) * 128 + ((64 + lg * 16) ^ ((lr & 7) << 4)));
        f32x4 zf = {0.f, 0.f, 0.f, 0.f};
        f32x4 s0 = mfma_(kf0, qf0, zf); s0 = mfma_(kf1, qf1, s0);
        f32x4 s1 = mfma_(kf2, qf0, zf); s1 = mfma_(kf3, qf1, s1);

        int cls = (k0 + 63 < qw0) ? 0 : ((k0 > qw0 + 47) ? 1 : 2);
        f32x4 p0v, p1v;
#pragma unroll
        for (int r = 0; r < 4; ++r) {
            int key0 = k0 + lg * 4 + r, key1 = key0 + 16;
            float r0, r1;
            if (cls == 0)      { r0 = qrel_lo; r1 = qrel_lo; }
            else if (cls == 1) { r0 = qrel_hi; r1 = qrel_hi; }
            else {
                int d0 = key0 - qg, d1 = key1 - qg;
                r0 = (d0 <= -32) ? qrel_lo : ((d0 >= 32) ? qrel_hi : b2f(qrow_rel[d0 + 32]));
                r1 = (d1 <= -32) ? qrel_lo : ((d1 >= 32) ? qrel_hi : b2f(qrow_rel[d1 + 32]));
            }
            p0v[r] = exp2f(s0[r] + r0 + b2f(maskB[key0]));   // scores in log2 domain
            p1v[r] = exp2f(s1[r] + r1 + b2f(maskB[key1]));
            l_run += p0v[r] + p1v[r];
        }
        // P -> LDS (packed b64 x2): elements [lg*4..] and [16+lg*4..]
        s16x4 pk0 = { (short)f2b(p0v[0]), (short)f2b(p0v[1]), (short)f2b(p0v[2]), (short)f2b(p0v[3]) };
        s16x4 pk1 = { (short)f2b(p1v[0]), (short)f2b(p1v[1]), (short)f2b(p1v[2]), (short)f2b(p1v[3]) };
        *(s16x4*)&P_lds[w][lr][lg * 4]      = pk0;
        *(s16x4*)&P_lds[w][lr][16 + lg * 4] = pk1;
        // arel buckets / tails
        if (cls == 2) {
#pragma unroll
            for (int r = 0; r < 4; ++r) {
                int key0 = k0 + lg * 4 + r, key1 = key0 + 16;
                int d0 = key0 - qg, d1 = key1 - qg;
                if (d0 > -32 && d0 < 32) arel_lds[w][lr][d0 + 32] = (u16)pk0[r];
                else if (d0 <= -32) tlo += p0v[r]; else thi += p0v[r];
                if (d1 > -32 && d1 < 32) arel_lds[w][lr][d1 + 32] = (u16)pk1[r];
                else if (d1 <= -32) tlo += p1v[r]; else thi += p1v[r];
            }
        } else {
            float s8 = (p0v[0] + p0v[1] + p0v[2] + p0v[3]) + (p1v[0] + p1v[1] + p1v[2] + p1v[3]);
            if (cls == 0) tlo += s8; else thi += s8;
        }
        // head-0 raw attn (rescaled by piggybacked rescale)
        if (h == 0) {
            long a0 = (long)((b << 10) + qg) * 1024 + k0 + lg * 4;
            if (f32f) {
                *(f32x4*)(attnF + a0) = p0v;
                *(f32x4*)(attnF + a0 + 16) = p1v;
            } else {
                *(s16x4*)(attnB + a0) = pk0;
                *(s16x4*)(attnB + a0 + 16) = pk1;
            }
        }
        __builtin_amdgcn_sched_barrier(0);
        // PV from LDS (swizzled V)
        bf8v pa = ld8(&P_lds[w][lr][lg * 8]);
#pragma unroll
        for (int dt = 0; dt < 4; ++dt) {
            bf8v vb = *(const bf8v*)(VB + (dt * 16 + lr) * 64 + ((lg * 16) ^ ((lr & 3) << 4)));
            acc[dt] = mfma_(pa, vb, acc[dt]);
        }
        __syncthreads();                   // drains stage(next) + all LDS reads of cur
    }

    // ---- reductions across lg (4 lanes per q-row) ----
    l_run += __shfl_xor(l_run, 16); l_run += __shfl_xor(l_run, 32);
    tlo   += __shfl_xor(tlo, 16);   tlo   += __shfl_xor(tlo, 32);
    thi   += __shfl_xor(thi, 16);   thi   += __shfl_xor(thi, 32);
    float inv_l = 1.0f / l_run;
    if (lg == 0) {
        linv_lds[w * 16 + lr] = inv_l;
        tlo_lds[w * 16 + lr] = tlo;
        thi_lds[w * 16 + lr] = thi;
        if (h == 0) linv_g[(b << 10) + qg] = f2b(inv_l);
    }

    // ctx += arel @ relT (buckets 1..63; bucket0/64 via rank-1 tails)
#pragma unroll
    for (int ks = 0; ks < 2; ++ks) {
        bf8v aa = ld8(&arel_lds[w][lr][ks * 32 + lg * 8]);
#pragma unroll
        for (int dt = 0; dt < 4; ++dt) {
            bf8v rb = ld8(relT + (dt * 16 + lr) * 64 + ks * 32 + lg * 8);
            acc[dt] = mfma_(aa, rb, acc[dt]);
        }
    }

    float r0v[4], r64v[4];
#pragma unroll
    for (int dt = 0; dt < 4; ++dt) {
        int d = dt * 16 + lr;
        r0v[dt]  = ldscalar(rel, d, f32f);
        r64v[dt] = ldscalar(rel, 64 * 64 + d, f32f);
    }

    // epilogue: rank-1 tails + normalize, write ctx (B,S,DM) bf16
#pragma unroll
    for (int dt = 0; dt < 4; ++dt) {
#pragma unroll
        for (int r = 0; r < 4; ++r) {
            int qrow = w * 16 + lg * 4 + r;
            float v = (acc[dt][r] + tlo_lds[qrow] * r0v[dt] + thi_lds[qrow] * r64v[dt])
                      * linv_lds[qrow];
            int qgr = q0 + qrow;
            ctx[((b << 10) + qgr) * 1024 + (h << 6) + dt * 16 + lr] = f2b(v);
        }
    }
}

// ======================= launch =======================
extern "C" void kernel_launch(void* const* d_in, const int* in_sizes, int n_in,
                              void* d_out, int out_size, void* d_ws, size_t ws_size,
                              hipStream_t stream) {
    const void* key   = d_in[0];
    const void* value = d_in[1];
    const void* query = d_in[2];
    const void* mask  = d_in[3];
    const void* Wq = d_in[4];  const void* bq = d_in[5];
    const void* Wk = d_in[6];  const void* bk = d_in[7];
    const void* Wv = d_in[8];  const void* bv = d_in[9];
    const void* Wo = d_in[10]; const void* bo = d_in[11];
    const void* rel = d_in[12];

    char* ws = (char*)d_ws;
    u16* WqT  = (u16*)(ws + 0 * MBYTE);
    u16* WkT  = (u16*)(ws + 2 * MBYTE);
    u16* WvT  = (u16*)(ws + 4 * MBYTE);
    u16* WoT  = (u16*)(ws + 6 * MBYTE);
    u16* Qws  = (u16*)(ws + 8 * MBYTE);
    u16* Kws  = (u16*)(ws + 16 * MBYTE);
    u16* Vtws = (u16*)(ws + 24 * MBYTE);
    u16* ctxw = (u16*)(ws + 32 * MBYTE);
    int* flags = (int*)(ws + 40 * MBYTE);
    u16* linv_g = (u16*)(ws + 40 * MBYTE + 16);   // 8KB

    u16* relT = (u16*)d_out;   // 8KB scratch in out-region; overwritten by final gemm

    sniffrelk<<<dim3(1), 256, 0, stream>>>((const u32*)query, (const u32*)mask, rel, relT, flags);
    tposek<<<dim3(16, 16, 4), 256, 0, stream>>>(Wq, Wk, Wv, Wo, WqT, WkT, WvT, WoT, flags);
    gemm128<<<dim3(768), 512, 0, stream>>>(query, key, value, WqT, WkT, WvT,
                                           bq, bk, bv, Qws, Kws, Vtws, 0, flags, 1,
                                           768, d_out, linv_g);
    attnk<<<dim3(1024), 256, 0, stream>>>(Qws, Kws, Vtws, rel, relT, mask,
                                          ctxw, d_out, linv_g, flags);
    // final gemm (256 blocks) + piggybacked attn rescale (128 blocks)
    gemm128<<<dim3(384), 512, 0, stream>>>(ctxw, ctxw, ctxw, WoT, WoT, WoT,
                                           bo, bo, bo, d_out, d_out, d_out, 3, flags, 0,
                                           256, d_out, linv_g);
}

// Round 23
// 171.487 us; speedup vs baseline: 1.0200x; 1.0200x over previous
//
#include <hip/hip_runtime.h>

typedef unsigned short u16;
typedef unsigned int   u32;
typedef short bf8v  __attribute__((ext_vector_type(8)));   // 8 bf16 as shorts
typedef short s16x4 __attribute__((ext_vector_type(4)));
typedef float f32x4 __attribute__((ext_vector_type(4)));

#define DEV static __device__ __forceinline__
#define MBYTE (1u<<20)

// ---- bf16 helpers (RNE) ----
DEV u16 f2b(float f) {
    u32 u = __builtin_bit_cast(u32, f);
    u32 r = (u + 0x7fffu + ((u >> 16) & 1u)) >> 16;
    return (u16)r;
}
DEV float b2f(u16 s) { return __builtin_bit_cast(float, (u32)s << 16); }
DEV bf8v ld8(const u16* p) { return *reinterpret_cast<const bf8v*>(p); }

// load 8 consecutive elements as bf16, from f32 or bf16 source
DEV bf8v ldelems(const void* X, long idx, int f32f) {
    if (f32f) {
        const float* p = (const float*)X + idx;
        f32x4 a = *(const f32x4*)p;
        f32x4 b = *(const f32x4*)(p + 4);
        bf8v r;
        r[0] = (short)f2b(a[0]); r[1] = (short)f2b(a[1]);
        r[2] = (short)f2b(a[2]); r[3] = (short)f2b(a[3]);
        r[4] = (short)f2b(b[0]); r[5] = (short)f2b(b[1]);
        r[6] = (short)f2b(b[2]); r[7] = (short)f2b(b[3]);
        return r;
    }
    return ld8((const u16*)X + idx);
}
DEV float ldscalar(const void* X, long idx, int f32f) {
    return f32f ? ((const float*)X)[idx] : b2f(((const u16*)X)[idx]);
}

DEV f32x4 mfma_(bf8v a, bf8v b, f32x4 c) {
    return __builtin_amdgcn_mfma_f32_16x16x32_bf16(a, b, c, 0, 0, 0);
}

// global -> LDS direct (16B per lane). LDS dest = wave-uniform base + lane*16.
DEV void gload16(void* lds, const void* g) {
    __builtin_amdgcn_global_load_lds(
        (const __attribute__((address_space(1))) void*)g,
        (__attribute__((address_space(3))) void*)lds,
        16, 0, 0);
}

// ================= dtype sniff + relT build (one block) =================
__global__ __launch_bounds__(256) void sniffrelk(const u32* q, const u32* m,
                                                 const void* rel, u16* relT, int* flags) {
    __shared__ int c1s, c2s;
    int t = threadIdx.x;
    if (t == 0) { c1s = 0; c2s = 0; }
    __syncthreads();
    int c1 = 0, c2 = 0;
    for (int i = t; i < 1024; i += 256) {
        u32 u = q[i];
        int e = (int)((u >> 23) & 0xff);
        if (u == 0u || (e >= 118 && e <= 134)) c1++;
        if (m[i] > 1u) c2++;
    }
    atomicAdd(&c1s, c1);
    atomicAdd(&c2s, c2);
    __syncthreads();
    int f32f = (c1s > 512) ? 1 : 0;
    if (t == 0) { flags[0] = f32f; flags[1] = (c2s > 100) ? 1 : 0; }
    for (int i = t; i < 64 * 64; i += 256) {
        int d = i >> 6, r = i & 63;
        relT[i] = f32f ? f2b(((const float*)rel)[r * 64 + d]) : ((const u16*)rel)[r * 64 + d];
    }
}

// ======================= weight transpose (64x64 tiles), dual-dtype src =======================
__global__ __launch_bounds__(256) void tposek(const void* s0, const void* s1,
                                              const void* s2, const void* s3,
                                              u16* d0, u16* d1, u16* d2, u16* d3,
                                              const int* flags) {
    __shared__ u16 tile[64][65];
    int f32f = flags[0];
    int z = blockIdx.z;
    const void* src = z == 0 ? s0 : (z == 1 ? s1 : (z == 2 ? s2 : s3));
    u16*       dst = z == 0 ? d0 : (z == 1 ? d1 : (z == 2 ? d2 : d3));
    int t = threadIdx.x;
    int r0 = blockIdx.y * 64, c0 = blockIdx.x * 64;
#pragma unroll
    for (int i = 0; i < 16; ++i) {
        int u = i * 256 + t;
        int row = u >> 6, col = u & 63;
        long gi = (long)(r0 + row) * 1024 + c0 + col;
        tile[row][col] = f32f ? f2b(((const float*)src)[gi]) : ((const u16*)src)[gi];
    }
    __syncthreads();
#pragma unroll
    for (int i = 0; i < 8; ++i) {
        int u = i * 256 + t;
        int row = u >> 5, col = (u & 31) * 2;
        u32 v = (u32)tile[col][row] | ((u32)tile[col + 1][row] << 16);
        *(u32*)(dst + (long)(c0 + row) * 1024 + r0 + col) = v;
    }
}

// ======= 128x128 bf16 GEMM, BK=32, 8 waves, XCD-panel-mapped, 2-phase dbuf =======
// Per iter: issue stage(next) -> compute(cur) -> write A(next) -> ONE barrier.
// LDS XOR-swizzle (both sides): logical slot s of row r at physical slot s^((r>>1)&3).
// Blocks with blockIdx.x >= gemm_nwg run the attn-rescale path (piggyback on idle CUs).
__global__ __launch_bounds__(512) void gemm128(
    const void* x0, const void* x1, const void* x2,
    const u16* w0, const u16* w1, const u16* w2,
    const void* b0, const void* b1, const void* b2,
    void* c0, void* c1, void* c2, int mode_base,
    const int* flags, int a_use_flag, int gemm_nwg,
    void* dout, const u16* linv_g) {
    __shared__ __align__(16) u16 Al[2][128 * 32];
    __shared__ __align__(16) u16 Bl[2][128 * 32];

    int j = blockIdx.x;
    int t = threadIdx.x;
    int f32m = flags[0];

    if (j >= gemm_nwg) {                    // ---- piggybacked attn rescale ----
        int rb = j - gemm_nwg;              // 0..127, each covers 32768 elements
#pragma unroll
        for (int i = 0; i < 8; ++i) {       // 8 * 512 * 8 = 32768 elements
            long e0 = ((long)rb * 32768) + (long)(i * 512 + t) * 8;
            float inv = b2f(linv_g[e0 >> 10]);
            if (f32m) {
                float* a = (float*)dout + 4194304 + e0;
                f32x4 v0 = *(f32x4*)a, v1 = *(f32x4*)(a + 4);
#pragma unroll
                for (int r = 0; r < 4; ++r) { v0[r] *= inv; v1[r] *= inv; }
                *(f32x4*)a = v0; *(f32x4*)(a + 4) = v1;
            } else {
                u16* a = (u16*)dout + 4194304 + e0;
                bf8v v = *(bf8v*)a;
                bf8v o;
#pragma unroll
                for (int r = 0; r < 8; ++r) o[r] = (short)f2b(b2f((u16)v[r]) * inv);
                *(bf8v*)a = o;
            }
        }
        return;
    }

    int nwg = gemm_nwg;
    int ppx = nwg >> 6;                     // panels per XCD (12 for QKV, 4 for out)
    int xcd = j & 7, idx = j >> 3;
    int panel = xcd * ppx + (idx >> 3);
    int n0 = (idx & 7) * 128;
    int m0 = (panel & 31) * 128;
    int z  = panel >> 5;

    const void* X    = z == 0 ? x0 : (z == 1 ? x1 : x2);
    const u16*  BT   = z == 0 ? w0 : (z == 1 ? w1 : w2);
    const void* bias = z == 0 ? b0 : (z == 1 ? b1 : b2);
    void*       C    = z == 0 ? c0 : (z == 1 ? c1 : c2);
    int mode = mode_base + z;
    int f32a = a_use_flag ? f32m : 0;

    int w = t >> 6, l = t & 63;
    int lr = l & 15, lg = l >> 4;
    int wr = (w >> 1) * 32, wc = (w & 1) * 64;   // wave quadrant: 32 rows x 64 cols

    int rS = t >> 2;                        // staging row 0..127
    int sP = t & 3;                         // physical 16B slot
    int sL = sP ^ ((rS >> 1) & 3);          // logical slot fetched by this thread

    f32x4 acc[2][4];
    f32x4 zf = {0.f, 0.f, 0.f, 0.f};
#pragma unroll
    for (int mt = 0; mt < 2; ++mt)
#pragma unroll
        for (int nt = 0; nt < 4; ++nt) acc[mt][nt] = zf;

    // prologue: stage K-slice 0 into buffer 0
    gload16((char*)Bl[0] + w * 1024,
            (const char*)BT + (long)(n0 + rS) * 2048 + sL * 16);
    bf8v va0 = ldelems(X, (long)(m0 + rS) * 1024 + sL * 8, f32a);
    *(bf8v*)((char*)Al[0] + rS * 64 + sP * 16) = va0;
    __syncthreads();

    int cur = 0;
    for (int kk = 0; kk < 32; ++kk) {
        int nxt = cur ^ 1;
        bf8v va_n;
        if (kk < 31) {                      // issue next-slice loads BEFORE compute
            gload16((char*)Bl[nxt] + w * 1024,
                    (const char*)BT + (long)(n0 + rS) * 2048 + (long)(kk + 1) * 64 + sL * 16);
            va_n = ldelems(X, (long)(m0 + rS) * 1024 + (kk + 1) * 32 + sL * 8, f32a);
        }
        bf8v af[2], bfr[4];
#pragma unroll
        for (int mt = 0; mt < 2; ++mt) {
            int r = wr + mt * 16 + lr;
            af[mt] = *(const bf8v*)((const char*)Al[cur] + r * 64 + ((lg * 16) ^ (((r >> 1) & 3) << 4)));
        }
#pragma unroll
        for (int nt = 0; nt < 4; ++nt) {
            int r = wc + nt * 16 + lr;
            bfr[nt] = *(const bf8v*)((const char*)Bl[cur] + r * 64 + ((lg * 16) ^ (((r >> 1) & 3) << 4)));
        }
#pragma unroll
        for (int mt = 0; mt < 2; ++mt)
#pragma unroll
            for (int nt = 0; nt < 4; ++nt) acc[mt][nt] = mfma_(af[mt], bfr[nt], acc[mt][nt]);
        if (kk < 31) *(bf8v*)((char*)Al[nxt] + rS * 64 + sP * 16) = va_n;
        __syncthreads();                    // single barrier: drains B DMA + A write, frees cur
        cur = nxt;
    }

#pragma unroll
    for (int nt = 0; nt < 4; ++nt) {
        int col = n0 + wc + nt * 16 + lr;
        float bv = f32m ? ((const float*)bias)[col] : b2f(((const u16*)bias)[col]);
#pragma unroll
        for (int mt = 0; mt < 2; ++mt) {
#pragma unroll
            for (int r = 0; r < 4; ++r) {
                int m = m0 + wr + mt * 16 + lg * 4 + r;
                float v = acc[mt][nt][r] + bv;
                if (mode == 0) v *= 0.125f;
                if (mode <= 1) {
                    int bb = m >> 10, s = m & 1023, hh = col >> 6, dd = col & 63;
                    ((u16*)C)[(((bb << 4) + hh) * 1024 + s) * 64 + dd] = f2b(v);
                } else if (mode == 2) {
                    int bb = m >> 10, s = m & 1023, hh = col >> 6, dd = col & 63;
                    ((u16*)C)[(((bb << 4) + hh) * 64 + dd) * 1024 + s] = f2b(v);
                } else {
                    long idx2 = (long)m * 1024 + col;
                    if (f32m) ((float*)C)[idx2] = v; else ((u16*)C)[idx2] = f2b(v);
                }
            }
        }
    }
}

// ======================= fused relative attention (single pass, max-free) =======================
__global__ __launch_bounds__(256) void attnk(
    const u16* __restrict__ Qw, const u16* __restrict__ Kw, const u16* __restrict__ Vtw,
    const void* __restrict__ rel, const u16* __restrict__ relT,
    const void* __restrict__ mask,
    u16* __restrict__ ctx, void* __restrict__ dout, u16* __restrict__ linv_g,
    const int* __restrict__ flags) {
    __shared__ __align__(16) u16 Klds[2][32 * 64];   // [chunk][key][d] 128B rows, swizzled
    __shared__ __align__(16) u16 Vlds[2][64 * 32];   // [chunk][d][key] 64B rows, swizzled
    __shared__ u16 qrelB[64][64];                    // qrel[q][i], i=0..63 (i=64 in regs)
    __shared__ __align__(16) u16 P_lds[4][16][40];
    __shared__ __align__(16) u16 arel_lds[4][16][64];
    __shared__ float linv_lds[64];
    __shared__ float tlo_lds[64], thi_lds[64];
    __shared__ u16 maskB[1024];

    int f32f = flags[0], m8 = flags[1];
    float* attnF = (float*)dout + 4194304;
    u16*   attnB = (u16*)dout + 4194304;

    int t = threadIdx.x, w = t >> 6, l = t & 63;
    int lr = l & 15, lg = l >> 4;
    int id = blockIdx.x;
    int xcd = id & 7, j = id >> 3;
    int bh = xcd * 8 + (j & 7);
    int qb = j >> 3;
    int b = bh >> 4, h = bh & 15;
    int q0 = qb * 64;
    int qw0 = q0 + w * 16;
    const u16* Qh  = Qw  + (((b << 4) + h) << 16);
    const u16* Kh  = Kw  + (((b << 4) + h) << 16);
    const u16* Vth = Vtw + (((b << 4) + h) << 16);

    // ---- stage chunk 0 ----
    int rowK = w * 8 + (l >> 3);
    int scK  = 16 * ((l & 7) ^ ((l >> 3) & 7));
    int rowV = w * 16 + (l >> 2);
    int scV  = ((l & 3) * 16) ^ (((l >> 2) & 3) << 4);
    gload16((char*)&Klds[0][0] + w * 1024, (const char*)Kh + (long)rowK * 128 + scK);
    gload16((char*)&Vlds[0][0] + w * 1024, (const char*)Vth + (long)rowV * 2048 + scV);

    // ---- init LDS (mask, arel zero) ----
    for (int i = t; i < 1024; i += 256) {
        int mv = m8 ? (int)((const unsigned char*)mask)[(b << 10) + i]
                    : ((const int*)mask)[(b << 10) + i];
        maskB[i] = mv ? f2b(-1.0e18f) : 0;
    }
#pragma unroll
    for (int i = 0; i < 8; ++i) ((u32*)&arel_lds[0][0][0])[t + i * 256] = 0;

    int qg = q0 + w * 16 + lr;             // this lane's query row
    bf8v qf0 = ld8(Qh + qg * 64 + lg * 8);
    bf8v qf1 = ld8(Qh + qg * 64 + 32 + lg * 8);

    // qrel[q][i] = Qs[q]·rel[i]  via mfma(rel, Q); store i=0..63 bf16, i=64 via shfl
    float lo_src = 0.f, hi_src = 0.f;
#pragma unroll
    for (int rt = 0; rt < 5; ++rt) {
        int rrow = rt * 16 + lr; if (rrow > 64) rrow = 64;
        f32x4 aq = {0.f, 0.f, 0.f, 0.f};
        aq = mfma_(ldelems(rel, rrow * 64 + lg * 8, f32f), qf0, aq);
        aq = mfma_(ldelems(rel, rrow * 64 + 32 + lg * 8, f32f), qf1, aq);
        if (rt < 4) {
#pragma unroll
            for (int r = 0; r < 4; ++r) qrelB[w * 16 + lr][rt * 16 + lg * 4 + r] = f2b(aq[r]);
            if (rt == 0) lo_src = aq[0];
        } else {
            hi_src = aq[0];
        }
    }
    float qrel_lo = __shfl(lo_src, lr);    // lane (lr, lg=0) holds qrel[lr][0]
    float qrel_hi = __shfl(hi_src, lr);
    const u16* qrow_rel = qrelB[w * 16 + lr];

    __syncthreads();                       // stage0 + LDS init complete

    float l_run = 0.f, tlo = 0.f, thi = 0.f;
    f32x4 acc[4];
#pragma unroll
    for (int dt = 0; dt < 4; ++dt) acc[dt] = f32x4{0.f, 0.f, 0.f, 0.f};

    for (int kc = 0; kc < 32; ++kc) {
        int cur = kc & 1;
        int k0 = kc * 32;
        if (kc < 31) {                     // stage next chunk
            int k1 = k0 + 32;
            gload16((char*)&Klds[cur ^ 1][0] + w * 1024,
                    (const char*)Kh + (long)(k1 + rowK) * 128 + scK);
            gload16((char*)&Vlds[cur ^ 1][0] + w * 1024,
                    (const char*)Vth + (long)rowV * 2048 + k1 * 2 + scV);
        }
        const char* KB = (const char*)&Klds[cur][0];
        const char* VB = (const char*)&Vlds[cur][0];

        // K fragments from LDS (swizzled)
        bf8v kf0 = *(const bf8v*)(KB + lr * 128 + ((lg * 16) ^ ((lr & 7) << 4)));
        bf8v kf1 = *(const bf8v*)(KB + lr * 128 + ((64 + lg * 16) ^ ((lr & 7) << 4)));
        bf8v kf2 = *(const bf8v*)(KB + (16 + lr) * 128 + ((lg * 16) ^ ((lr & 7) << 4)));
        bf8v kf3 = *(const bf8v*)(KB + (16 + lr) * 128 + ((64 + lg * 16) ^ ((lr & 7) << 4)));
        f32x4 zf = {0.f, 0.f, 0.f, 0.f};
        f32x4 s0 = mfma_(kf0, qf0, zf); s0 = mfma_(kf1, qf1, s0);
        f32x4 s1 = mfma_(kf2, qf0, zf); s1 = mfma_(kf3, qf1, s1);

        int cls = (k0 + 63 < qw0) ? 0 : ((k0 > qw0 + 47) ? 1 : 2);
        f32x4 p0v, p1v;
#pragma unroll
        for (int r = 0; r < 4; ++r) {
            int key0 = k0 + lg * 4 + r, key1 = key0 + 16;
            float r0, r1;
            if (cls == 0)      { r0 = qrel_lo; r1 = qrel_lo; }
            else if (cls == 1) { r0 = qrel_hi; r1 = qrel_hi; }
            else {
                int d0 = key0 - qg, d1 = key1 - qg;
                r0 = (d0 <= -32) ? qrel_lo : ((d0 >= 32) ? qrel_hi : b2f(qrow_rel[d0 + 32]));
                r1 = (d1 <= -32) ? qrel_lo : ((d1 >= 32) ? qrel_hi : b2f(qrow_rel[d1 + 32]));
            }
            p0v[r] = __expf(s0[r] + r0 + b2f(maskB[key0]));
            p1v[r] = __expf(s1[r] + r1 + b2f(maskB[key1]));
            l_run += p0v[r] + p1v[r];
        }
        // P -> LDS (packed b64 x2): elements [lg*4..] and [16+lg*4..]
        s16x4 pk0 = { (short)f2b(p0v[0]), (short)f2b(p0v[1]), (short)f2b(p0v[2]), (short)f2b(p0v[3]) };
        s16x4 pk1 = { (short)f2b(p1v[0]), (short)f2b(p1v[1]), (short)f2b(p1v[2]), (short)f2b(p1v[3]) };
        *(s16x4*)&P_lds[w][lr][lg * 4]      = pk0;
        *(s16x4*)&P_lds[w][lr][16 + lg * 4] = pk1;
        // arel buckets / tails
        if (cls == 2) {
#pragma unroll
            for (int r = 0; r < 4; ++r) {
                int key0 = k0 + lg * 4 + r, key1 = key0 + 16;
                int d0 = key0 - qg, d1 = key1 - qg;
                if (d0 > -32 && d0 < 32) arel_lds[w][lr][d0 + 32] = (u16)pk0[r];
                else if (d0 <= -32) tlo += p0v[r]; else thi += p0v[r];
                if (d1 > -32 && d1 < 32) arel_lds[w][lr][d1 + 32] = (u16)pk1[r];
                else if (d1 <= -32) tlo += p1v[r]; else thi += p1v[r];
            }
        } else {
            float s8 = (p0v[0] + p0v[1] + p0v[2] + p0v[3]) + (p1v[0] + p1v[1] + p1v[2] + p1v[3]);
            if (cls == 0) tlo += s8; else thi += s8;
        }
        // head-0 raw attn (rescaled by piggybacked rescale)
        if (h == 0) {
            long a0 = (long)((b << 10) + qg) * 1024 + k0 + lg * 4;
            if (f32f) {
                *(f32x4*)(attnF + a0) = p0v;
                *(f32x4*)(attnF + a0 + 16) = p1v;
            } else {
                *(s16x4*)(attnB + a0) = pk0;
                *(s16x4*)(attnB + a0 + 16) = pk1;
            }
        }
        __builtin_amdgcn_sched_barrier(0);
        // PV from LDS (swizzled V)
        bf8v pa = ld8(&P_lds[w][lr][lg * 8]);
#pragma unroll
        for (int dt = 0; dt < 4; ++dt) {
            bf8v vb = *(const bf8v*)(VB + (dt * 16 + lr) * 64 + ((lg * 16) ^ ((lr & 3) << 4)));
            acc[dt] = mfma_(pa, vb, acc[dt]);
        }
        __syncthreads();                   // drains stage(next) + all LDS reads of cur
    }

    // ---- reductions across lg (4 lanes per q-row) ----
    l_run += __shfl_xor(l_run, 16); l_run += __shfl_xor(l_run, 32);
    tlo   += __shfl_xor(tlo, 16);   tlo   += __shfl_xor(tlo, 32);
    thi   += __shfl_xor(thi, 16);   thi   += __shfl_xor(thi, 32);
    float inv_l = 1.0f / l_run;
    if (lg == 0) {
        linv_lds[w * 16 + lr] = inv_l;
        tlo_lds[w * 16 + lr] = tlo;
        thi_lds[w * 16 + lr] = thi;
        if (h == 0) linv_g[(b << 10) + qg] = f2b(inv_l);
    }

    // ctx += arel @ relT (buckets 1..63; bucket0/64 via rank-1 tails)
#pragma unroll
    for (int ks = 0; ks < 2; ++ks) {
        bf8v aa = ld8(&arel_lds[w][lr][ks * 32 + lg * 8]);
#pragma unroll
        for (int dt = 0; dt < 4; ++dt) {
            bf8v rb = ld8(relT + (dt * 16 + lr) * 64 + ks * 32 + lg * 8);
            acc[dt] = mfma_(aa, rb, acc[dt]);
        }
    }

    float r0v[4], r64v[4];
#pragma unroll
    for (int dt = 0; dt < 4; ++dt) {
        int d = dt * 16 + lr;
        r0v[dt]  = ldscalar(rel, d, f32f);
        r64v[dt] = ldscalar(rel, 64 * 64 + d, f32f);
    }

    // epilogue: rank-1 tails + normalize, write ctx (B,S,DM) bf16
#pragma unroll
    for (int dt = 0; dt < 4; ++dt) {
#pragma unroll
        for (int r = 0; r < 4; ++r) {
            int qrow = w * 16 + lg * 4 + r;
            float v = (acc[dt][r] + tlo_lds[qrow] * r0v[dt] + thi_lds[qrow] * r64v[dt])
                      * linv_lds[qrow];
            int qgr = q0 + qrow;
            ctx[((b << 10) + qgr) * 1024 + (h << 6) + dt * 16 + lr] = f2b(v);
        }
    }
}

// ======================= launch =======================
extern "C" void kernel_launch(void* const* d_in, const int* in_sizes, int n_in,
                              void* d_out, int out_size, void* d_ws, size_t ws_size,
                              hipStream_t stream) {
    const void* key   = d_in[0];
    const void* value = d_in[1];
    const void* query = d_in[2];
    const void* mask  = d_in[3];
    const void* Wq = d_in[4];  const void* bq = d_in[5];
    const void* Wk = d_in[6];  const void* bk = d_in[7];
    const void* Wv = d_in[8];  const void* bv = d_in[9];
    const void* Wo = d_in[10]; const void* bo = d_in[11];
    const void* rel = d_in[12];

    char* ws = (char*)d_ws;
    u16* WqT  = (u16*)(ws + 0 * MBYTE);
    u16* WkT  = (u16*)(ws + 2 * MBYTE);
    u16* WvT  = (u16*)(ws + 4 * MBYTE);
    u16* WoT  = (u16*)(ws + 6 * MBYTE);
    u16* Qws  = (u16*)(ws + 8 * MBYTE);
    u16* Kws  = (u16*)(ws + 16 * MBYTE);
    u16* Vtws = (u16*)(ws + 24 * MBYTE);
    u16* ctxw = (u16*)(ws + 32 * MBYTE);
    int* flags = (int*)(ws + 40 * MBYTE);
    u16* linv_g = (u16*)(ws + 40 * MBYTE + 16);   // 8KB

    u16* relT = (u16*)d_out;   // 8KB scratch in out-region; overwritten by final gemm

    sniffrelk<<<dim3(1), 256, 0, stream>>>((const u32*)query, (const u32*)mask, rel, relT, flags);
    tposek<<<dim3(16, 16, 4), 256, 0, stream>>>(Wq, Wk, Wv, Wo, WqT, WkT, WvT, WoT, flags);
    gemm128<<<dim3(768), 512, 0, stream>>>(query, key, value, WqT, WkT, WvT,
                                           bq, bk, bv, Qws, Kws, Vtws, 0, flags, 1,
                                           768, d_out, linv_g);
    attnk<<<dim3(1024), 256, 0, stream>>>(Qws, Kws, Vtws, rel, relT, mask,
                                          ctxw, d_out, linv_g, flags);
    // final gemm (256 blocks) + piggybacked attn rescale (128 blocks)
    gemm128<<<dim3(384), 512, 0, stream>>>(ctxw, ctxw, ctxw, WoT, WoT, WoT,
                                           bo, bo, bo, d_out, d_out, d_out, 3, flags, 0,
                                           256, d_out, linv_g);
}

// Round 24
// 170.665 us; speedup vs baseline: 1.0249x; 1.0048x over previous
//
#include <hip/hip_runtime.h>

typedef unsigned short u16;
typedef unsigned int   u32;
typedef short bf8v  __attribute__((ext_vector_type(8)));   // 8 bf16 as shorts
typedef short s16x4 __attribute__((ext_vector_type(4)));
typedef float f32x4 __attribute__((ext_vector_type(4)));

#define DEV static __device__ __forceinline__
#define MBYTE (1u<<20)

// ---- bf16 helpers (RNE) ----
DEV u16 f2b(float f) {
    u32 u = __builtin_bit_cast(u32, f);
    u32 r = (u + 0x7fffu + ((u >> 16) & 1u)) >> 16;
    return (u16)r;
}
DEV float b2f(u16 s) { return __builtin_bit_cast(float, (u32)s << 16); }
DEV bf8v ld8(const u16* p) { return *reinterpret_cast<const bf8v*>(p); }

// load 8 consecutive elements as bf16, from f32 or bf16 source
DEV bf8v ldelems(const void* X, long idx, int f32f) {
    if (f32f) {
        const float* p = (const float*)X + idx;
        f32x4 a = *(const f32x4*)p;
        f32x4 b = *(const f32x4*)(p + 4);
        bf8v r;
        r[0] = (short)f2b(a[0]); r[1] = (short)f2b(a[1]);
        r[2] = (short)f2b(a[2]); r[3] = (short)f2b(a[3]);
        r[4] = (short)f2b(b[0]); r[5] = (short)f2b(b[1]);
        r[6] = (short)f2b(b[2]); r[7] = (short)f2b(b[3]);
        return r;
    }
    return ld8((const u16*)X + idx);
}
DEV float ldscalar(const void* X, long idx, int f32f) {
    return f32f ? ((const float*)X)[idx] : b2f(((const u16*)X)[idx]);
}

DEV f32x4 mfma_(bf8v a, bf8v b, f32x4 c) {
    return __builtin_amdgcn_mfma_f32_16x16x32_bf16(a, b, c, 0, 0, 0);
}

// global -> LDS direct (16B per lane). LDS dest = wave-uniform base + lane*16.
DEV void gload16(void* lds, const void* g) {
    __builtin_amdgcn_global_load_lds(
        (const __attribute__((address_space(1))) void*)g,
        (__attribute__((address_space(3))) void*)lds,
        16, 0, 0);
}

// ================= dtype sniff + relT build (one block) =================
__global__ __launch_bounds__(256) void sniffrelk(const u32* q, const u32* m,
                                                 const void* rel, u16* relT, int* flags) {
    __shared__ int c1s, c2s;
    int t = threadIdx.x;
    if (t == 0) { c1s = 0; c2s = 0; }
    __syncthreads();
    int c1 = 0, c2 = 0;
    for (int i = t; i < 1024; i += 256) {
        u32 u = q[i];
        int e = (int)((u >> 23) & 0xff);
        if (u == 0u || (e >= 118 && e <= 134)) c1++;
        if (m[i] > 1u) c2++;
    }
    atomicAdd(&c1s, c1);
    atomicAdd(&c2s, c2);
    __syncthreads();
    int f32f = (c1s > 512) ? 1 : 0;
    if (t == 0) { flags[0] = f32f; flags[1] = (c2s > 100) ? 1 : 0; }
    for (int i = t; i < 64 * 64; i += 256) {
        int d = i >> 6, r = i & 63;
        relT[i] = f32f ? f2b(((const float*)rel)[r * 64 + d]) : ((const u16*)rel)[r * 64 + d];
    }
}

// ======================= weight transpose (64x64 tiles), dual-dtype src =======================
__global__ __launch_bounds__(256) void tposek(const void* s0, const void* s1,
                                              const void* s2, const void* s3,
                                              u16* d0, u16* d1, u16* d2, u16* d3,
                                              const int* flags) {
    __shared__ u16 tile[64][65];
    int f32f = flags[0];
    int z = blockIdx.z;
    const void* src = z == 0 ? s0 : (z == 1 ? s1 : (z == 2 ? s2 : s3));
    u16*       dst = z == 0 ? d0 : (z == 1 ? d1 : (z == 2 ? d2 : d3));
    int t = threadIdx.x;
    int r0 = blockIdx.y * 64, c0 = blockIdx.x * 64;
#pragma unroll
    for (int i = 0; i < 16; ++i) {
        int u = i * 256 + t;
        int row = u >> 6, col = u & 63;
        long gi = (long)(r0 + row) * 1024 + c0 + col;
        tile[row][col] = f32f ? f2b(((const float*)src)[gi]) : ((const u16*)src)[gi];
    }
    __syncthreads();
#pragma unroll
    for (int i = 0; i < 8; ++i) {
        int u = i * 256 + t;
        int row = u >> 5, col = (u & 31) * 2;
        u32 v = (u32)tile[col][row] | ((u32)tile[col + 1][row] << 16);
        *(u32*)(dst + (long)(c0 + row) * 1024 + r0 + col) = v;
    }
}

// ======= 128x128 bf16 GEMM, BK=32, 8 waves, XCD-panel-mapped, 2-phase dbuf =======
// Per iter: issue stage(next) -> compute(cur) -> write A(next) -> ONE barrier.
// LDS XOR-swizzle (both sides): logical slot s of row r at physical slot s^((r>>1)&3).
// Blocks with blockIdx.x >= gemm_nwg run the attn-rescale path (piggyback on idle CUs).
__global__ __launch_bounds__(512) void gemm128(
    const void* x0, const void* x1, const void* x2,
    const u16* w0, const u16* w1, const u16* w2,
    const void* b0, const void* b1, const void* b2,
    void* c0, void* c1, void* c2, int mode_base,
    const int* flags, int a_use_flag, int gemm_nwg,
    void* dout, const u16* linv_g) {
    __shared__ __align__(16) u16 Al[2][128 * 32];
    __shared__ __align__(16) u16 Bl[2][128 * 32];

    int j = blockIdx.x;
    int t = threadIdx.x;
    int f32m = flags[0];

    if (j >= gemm_nwg) {                    // ---- piggybacked attn rescale ----
        int rb = j - gemm_nwg;              // 0..127, each covers 32768 elements
#pragma unroll
        for (int i = 0; i < 8; ++i) {       // 8 * 512 * 8 = 32768 elements
            long e0 = ((long)rb * 32768) + (long)(i * 512 + t) * 8;
            float inv = b2f(linv_g[e0 >> 10]);
            if (f32m) {
                float* a = (float*)dout + 4194304 + e0;
                f32x4 v0 = *(f32x4*)a, v1 = *(f32x4*)(a + 4);
#pragma unroll
                for (int r = 0; r < 4; ++r) { v0[r] *= inv; v1[r] *= inv; }
                *(f32x4*)a = v0; *(f32x4*)(a + 4) = v1;
            } else {
                u16* a = (u16*)dout + 4194304 + e0;
                bf8v v = *(bf8v*)a;
                bf8v o;
#pragma unroll
                for (int r = 0; r < 8; ++r) o[r] = (short)f2b(b2f((u16)v[r]) * inv);
                *(bf8v*)a = o;
            }
        }
        return;
    }

    int nwg = gemm_nwg;
    int ppx = nwg >> 6;                     // panels per XCD (12 for QKV, 4 for out)
    int xcd = j & 7, idx = j >> 3;
    int panel = xcd * ppx + (idx >> 3);
    int n0 = (idx & 7) * 128;
    int m0 = (panel & 31) * 128;
    int z  = panel >> 5;

    const void* X    = z == 0 ? x0 : (z == 1 ? x1 : x2);
    const u16*  BT   = z == 0 ? w0 : (z == 1 ? w1 : w2);
    const void* bias = z == 0 ? b0 : (z == 1 ? b1 : b2);
    void*       C    = z == 0 ? c0 : (z == 1 ? c1 : c2);
    int mode = mode_base + z;
    int f32a = a_use_flag ? f32m : 0;

    int w = t >> 6, l = t & 63;
    int lr = l & 15, lg = l >> 4;
    int wr = (w >> 1) * 32, wc = (w & 1) * 64;   // wave quadrant: 32 rows x 64 cols

    int rS = t >> 2;                        // staging row 0..127
    int sP = t & 3;                         // physical 16B slot
    int sL = sP ^ ((rS >> 1) & 3);          // logical slot fetched by this thread

    f32x4 acc[2][4];
    f32x4 zf = {0.f, 0.f, 0.f, 0.f};
#pragma unroll
    for (int mt = 0; mt < 2; ++mt)
#pragma unroll
        for (int nt = 0; nt < 4; ++nt) acc[mt][nt] = zf;

    // prologue: stage K-slice 0 into buffer 0
    gload16((char*)Bl[0] + w * 1024,
            (const char*)BT + (long)(n0 + rS) * 2048 + sL * 16);
    bf8v va0 = ldelems(X, (long)(m0 + rS) * 1024 + sL * 8, f32a);
    *(bf8v*)((char*)Al[0] + rS * 64 + sP * 16) = va0;
    __syncthreads();

    int cur = 0;
    for (int kk = 0; kk < 32; ++kk) {
        int nxt = cur ^ 1;
        bf8v va_n;
        if (kk < 31) {                      // issue next-slice loads BEFORE compute
            gload16((char*)Bl[nxt] + w * 1024,
                    (const char*)BT + (long)(n0 + rS) * 2048 + (long)(kk + 1) * 64 + sL * 16);
            va_n = ldelems(X, (long)(m0 + rS) * 1024 + (kk + 1) * 32 + sL * 8, f32a);
        }
        bf8v af[2], bfr[4];
#pragma unroll
        for (int mt = 0; mt < 2; ++mt) {
            int r = wr + mt * 16 + lr;
            af[mt] = *(const bf8v*)((const char*)Al[cur] + r * 64 + ((lg * 16) ^ (((r >> 1) & 3) << 4)));
        }
#pragma unroll
        for (int nt = 0; nt < 4; ++nt) {
            int r = wc + nt * 16 + lr;
            bfr[nt] = *(const bf8v*)((const char*)Bl[cur] + r * 64 + ((lg * 16) ^ (((r >> 1) & 3) << 4)));
        }
#pragma unroll
        for (int mt = 0; mt < 2; ++mt)
#pragma unroll
            for (int nt = 0; nt < 4; ++nt) acc[mt][nt] = mfma_(af[mt], bfr[nt], acc[mt][nt]);
        if (kk < 31) *(bf8v*)((char*)Al[nxt] + rS * 64 + sP * 16) = va_n;
        __syncthreads();                    // single barrier: drains B DMA + A write, frees cur
        cur = nxt;
    }

#pragma unroll
    for (int nt = 0; nt < 4; ++nt) {
        int col = n0 + wc + nt * 16 + lr;
        float bv = f32m ? ((const float*)bias)[col] : b2f(((const u16*)bias)[col]);
#pragma unroll
        for (int mt = 0; mt < 2; ++mt) {
#pragma unroll
            for (int r = 0; r < 4; ++r) {
                int m = m0 + wr + mt * 16 + lg * 4 + r;
                float v = acc[mt][nt][r] + bv;
                if (mode == 0) v *= 0.125f;
                if (mode <= 1) {
                    int bb = m >> 10, s = m & 1023, hh = col >> 6, dd = col & 63;
                    ((u16*)C)[(((bb << 4) + hh) * 1024 + s) * 64 + dd] = f2b(v);
                } else if (mode == 2) {
                    int bb = m >> 10, s = m & 1023, hh = col >> 6, dd = col & 63;
                    ((u16*)C)[(((bb << 4) + hh) * 64 + dd) * 1024 + s] = f2b(v);
                } else {
                    long idx2 = (long)m * 1024 + col;
                    if (f32m) ((float*)C)[idx2] = v; else ((u16*)C)[idx2] = f2b(v);
                }
            }
        }
    }
}

// ======================= fused relative attention (single pass, max-free) =======================
__global__ __launch_bounds__(256) void attnk(
    const u16* __restrict__ Qw, const u16* __restrict__ Kw, const u16* __restrict__ Vtw,
    const void* __restrict__ rel, const u16* __restrict__ relT,
    const void* __restrict__ mask,
    u16* __restrict__ ctx, void* __restrict__ dout, u16* __restrict__ linv_g,
    const int* __restrict__ flags) {
    __shared__ __align__(16) u16 Klds[2][32 * 64];   // [chunk][key][d] 128B rows, swizzled
    __shared__ __align__(16) u16 Vlds[2][64 * 32];   // [chunk][d][key] 64B rows, swizzled
    __shared__ u16 qrelB[64][64];                    // qrel[q][i], i=0..63 (i=64 in regs)
    __shared__ __align__(16) u16 P_lds[4][16][40];
    __shared__ __align__(16) u16 arel_lds[4][16][64];
    __shared__ float linv_lds[64];
    __shared__ float tlo_lds[64], thi_lds[64];
    __shared__ u16 maskB[1024];

    int f32f = flags[0], m8 = flags[1];
    float* attnF = (float*)dout + 4194304;
    u16*   attnB = (u16*)dout + 4194304;

    int t = threadIdx.x, w = t >> 6, l = t & 63;
    int lr = l & 15, lg = l >> 4;
    int id = blockIdx.x;
    int xcd = id & 7, j = id >> 3;
    int bh = xcd * 8 + (j & 7);
    int qb = j >> 3;
    int b = bh >> 4, h = bh & 15;
    int q0 = qb * 64;
    int qw0 = q0 + w * 16;
    const u16* Qh  = Qw  + (((b << 4) + h) << 16);
    const u16* Kh  = Kw  + (((b << 4) + h) << 16);
    const u16* Vth = Vtw + (((b << 4) + h) << 16);

    // ---- stage chunk 0 ----
    // V swizzle key = (row>>2)&3; staging row = w*16 + (l>>2) so key = (l>>4)&3.
    int rowK = w * 8 + (l >> 3);
    int scK  = 16 * ((l & 7) ^ ((l >> 3) & 7));
    int rowV = w * 16 + (l >> 2);
    int scV  = ((l & 3) * 16) ^ (((l >> 4) & 3) << 4);
    gload16((char*)&Klds[0][0] + w * 1024, (const char*)Kh + (long)rowK * 128 + scK);
    gload16((char*)&Vlds[0][0] + w * 1024, (const char*)Vth + (long)rowV * 2048 + scV);

    // ---- init LDS (mask, arel zero) ----
    for (int i = t; i < 1024; i += 256) {
        int mv = m8 ? (int)((const unsigned char*)mask)[(b << 10) + i]
                    : ((const int*)mask)[(b << 10) + i];
        maskB[i] = mv ? f2b(-1.0e18f) : 0;
    }
#pragma unroll
    for (int i = 0; i < 8; ++i) ((u32*)&arel_lds[0][0][0])[t + i * 256] = 0;

    int qg = q0 + w * 16 + lr;             // this lane's query row
    bf8v qf0 = ld8(Qh + qg * 64 + lg * 8);
    bf8v qf1 = ld8(Qh + qg * 64 + 32 + lg * 8);

    // qrel[q][i] = Qs[q]·rel[i]  via mfma(rel, Q); store i=0..63 bf16, i=64 via shfl
    float lo_src = 0.f, hi_src = 0.f;
#pragma unroll
    for (int rt = 0; rt < 5; ++rt) {
        int rrow = rt * 16 + lr; if (rrow > 64) rrow = 64;
        f32x4 aq = {0.f, 0.f, 0.f, 0.f};
        aq = mfma_(ldelems(rel, rrow * 64 + lg * 8, f32f), qf0, aq);
        aq = mfma_(ldelems(rel, rrow * 64 + 32 + lg * 8, f32f), qf1, aq);
        if (rt < 4) {
#pragma unroll
            for (int r = 0; r < 4; ++r) qrelB[w * 16 + lr][rt * 16 + lg * 4 + r] = f2b(aq[r]);
            if (rt == 0) lo_src = aq[0];
        } else {
            hi_src = aq[0];
        }
    }
    float qrel_lo = __shfl(lo_src, lr);    // lane (lr, lg=0) holds qrel[lr][0]
    float qrel_hi = __shfl(hi_src, lr);
    const u16* qrow_rel = qrelB[w * 16 + lr];

    __syncthreads();                       // stage0 + LDS init complete

    float l_run = 0.f, tlo = 0.f, thi = 0.f;
    f32x4 acc[4];
#pragma unroll
    for (int dt = 0; dt < 4; ++dt) acc[dt] = f32x4{0.f, 0.f, 0.f, 0.f};

    for (int kc = 0; kc < 32; ++kc) {
        int cur = kc & 1;
        int k0 = kc * 32;
        if (kc < 31) {                     // stage next chunk
            int k1 = k0 + 32;
            gload16((char*)&Klds[cur ^ 1][0] + w * 1024,
                    (const char*)Kh + (long)(k1 + rowK) * 128 + scK);
            gload16((char*)&Vlds[cur ^ 1][0] + w * 1024,
                    (const char*)Vth + (long)rowV * 2048 + k1 * 2 + scV);
        }
        const char* KB = (const char*)&Klds[cur][0];
        const char* VB = (const char*)&Vlds[cur][0];

        // K fragments from LDS (swizzled)
        bf8v kf0 = *(const bf8v*)(KB + lr * 128 + ((lg * 16) ^ ((lr & 7) << 4)));
        bf8v kf1 = *(const bf8v*)(KB + lr * 128 + ((64 + lg * 16) ^ ((lr & 7) << 4)));
        bf8v kf2 = *(const bf8v*)(KB + (16 + lr) * 128 + ((lg * 16) ^ ((lr & 7) << 4)));
        bf8v kf3 = *(const bf8v*)(KB + (16 + lr) * 128 + ((64 + lg * 16) ^ ((lr & 7) << 4)));
        f32x4 zf = {0.f, 0.f, 0.f, 0.f};
        f32x4 s0 = mfma_(kf0, qf0, zf); s0 = mfma_(kf1, qf1, s0);
        f32x4 s1 = mfma_(kf2, qf0, zf); s1 = mfma_(kf3, qf1, s1);

        int cls = (k0 + 63 < qw0) ? 0 : ((k0 > qw0 + 47) ? 1 : 2);
        f32x4 p0v, p1v;
#pragma unroll
        for (int r = 0; r < 4; ++r) {
            int key0 = k0 + lg * 4 + r, key1 = key0 + 16;
            float r0, r1;
            if (cls == 0)      { r0 = qrel_lo; r1 = qrel_lo; }
            else if (cls == 1) { r0 = qrel_hi; r1 = qrel_hi; }
            else {
                int d0 = key0 - qg, d1 = key1 - qg;
                r0 = (d0 <= -32) ? qrel_lo : ((d0 >= 32) ? qrel_hi : b2f(qrow_rel[d0 + 32]));
                r1 = (d1 <= -32) ? qrel_lo : ((d1 >= 32) ? qrel_hi : b2f(qrow_rel[d1 + 32]));
            }
            p0v[r] = __expf(s0[r] + r0 + b2f(maskB[key0]));
            p1v[r] = __expf(s1[r] + r1 + b2f(maskB[key1]));
            l_run += p0v[r] + p1v[r];
        }
        // P -> LDS (packed b64 x2): elements [lg*4..] and [16+lg*4..]
        s16x4 pk0 = { (short)f2b(p0v[0]), (short)f2b(p0v[1]), (short)f2b(p0v[2]), (short)f2b(p0v[3]) };
        s16x4 pk1 = { (short)f2b(p1v[0]), (short)f2b(p1v[1]), (short)f2b(p1v[2]), (short)f2b(p1v[3]) };
        *(s16x4*)&P_lds[w][lr][lg * 4]      = pk0;
        *(s16x4*)&P_lds[w][lr][16 + lg * 4] = pk1;
        // arel buckets / tails
        if (cls == 2) {
#pragma unroll
            for (int r = 0; r < 4; ++r) {
                int key0 = k0 + lg * 4 + r, key1 = key0 + 16;
                int d0 = key0 - qg, d1 = key1 - qg;
                if (d0 > -32 && d0 < 32) arel_lds[w][lr][d0 + 32] = (u16)pk0[r];
                else if (d0 <= -32) tlo += p0v[r]; else thi += p0v[r];
                if (d1 > -32 && d1 < 32) arel_lds[w][lr][d1 + 32] = (u16)pk1[r];
                else if (d1 <= -32) tlo += p1v[r]; else thi += p1v[r];
            }
        } else {
            float s8 = (p0v[0] + p0v[1] + p0v[2] + p0v[3]) + (p1v[0] + p1v[1] + p1v[2] + p1v[3]);
            if (cls == 0) tlo += s8; else thi += s8;
        }
        // head-0 raw attn (rescaled by piggybacked rescale)
        if (h == 0) {
            long a0 = (long)((b << 10) + qg) * 1024 + k0 + lg * 4;
            if (f32f) {
                *(f32x4*)(attnF + a0) = p0v;
                *(f32x4*)(attnF + a0 + 16) = p1v;
            } else {
                *(s16x4*)(attnB + a0) = pk0;
                *(s16x4*)(attnB + a0 + 16) = pk1;
            }
        }
        __builtin_amdgcn_sched_barrier(0);
        // PV from LDS (V swizzled with key (row>>2)&3 = (lr>>2)&3)
        bf8v pa = ld8(&P_lds[w][lr][lg * 8]);
#pragma unroll
        for (int dt = 0; dt < 4; ++dt) {
            bf8v vb = *(const bf8v*)(VB + (dt * 16 + lr) * 64 + ((lg * 16) ^ (((lr >> 2) & 3) << 4)));
            acc[dt] = mfma_(pa, vb, acc[dt]);
        }
        __syncthreads();                   // drains stage(next) + all LDS reads of cur
    }

    // ---- reductions across lg (4 lanes per q-row) ----
    l_run += __shfl_xor(l_run, 16); l_run += __shfl_xor(l_run, 32);
    tlo   += __shfl_xor(tlo, 16);   tlo   += __shfl_xor(tlo, 32);
    thi   += __shfl_xor(thi, 16);   thi   += __shfl_xor(thi, 32);
    float inv_l = 1.0f / l_run;
    if (lg == 0) {
        linv_lds[w * 16 + lr] = inv_l;
        tlo_lds[w * 16 + lr] = tlo;
        thi_lds[w * 16 + lr] = thi;
        if (h == 0) linv_g[(b << 10) + qg] = f2b(inv_l);
    }

    // ctx += arel @ relT (buckets 1..63; bucket0/64 via rank-1 tails)
#pragma unroll
    for (int ks = 0; ks < 2; ++ks) {
        bf8v aa = ld8(&arel_lds[w][lr][ks * 32 + lg * 8]);
#pragma unroll
        for (int dt = 0; dt < 4; ++dt) {
            bf8v rb = ld8(relT + (dt * 16 + lr) * 64 + ks * 32 + lg * 8);
            acc[dt] = mfma_(aa, rb, acc[dt]);
        }
    }

    float r0v[4], r64v[4];
#pragma unroll
    for (int dt = 0; dt < 4; ++dt) {
        int d = dt * 16 + lr;
        r0v[dt]  = ldscalar(rel, d, f32f);
        r64v[dt] = ldscalar(rel, 64 * 64 + d, f32f);
    }

    // epilogue: rank-1 tails + normalize, write ctx (B,S,DM) bf16
#pragma unroll
    for (int dt = 0; dt < 4; ++dt) {
#pragma unroll
        for (int r = 0; r < 4; ++r) {
            int qrow = w * 16 + lg * 4 + r;
            float v = (acc[dt][r] + tlo_lds[qrow] * r0v[dt] + thi_lds[qrow] * r64v[dt])
                      * linv_lds[qrow];
            int qgr = q0 + qrow;
            ctx[((b << 10) + qgr) * 1024 + (h << 6) + dt * 16 + lr] = f2b(v);
        }
    }
}

// ======================= launch =======================
extern "C" void kernel_launch(void* const* d_in, const int* in_sizes, int n_in,
                              void* d_out, int out_size, void* d_ws, size_t ws_size,
                              hipStream_t stream) {
    const void* key   = d_in[0];
    const void* value = d_in[1];
    const void* query = d_in[2];
    const void* mask  = d_in[3];
    const void* Wq = d_in[4];  const void* bq = d_in[5];
    const void* Wk = d_in[6];  const void* bk = d_in[7];
    const void* Wv = d_in[8];  const void* bv = d_in[9];
    const void* Wo = d_in[10]; const void* bo = d_in[11];
    const void* rel = d_in[12];

    char* ws = (char*)d_ws;
    u16* WqT  = (u16*)(ws + 0 * MBYTE);
    u16* WkT  = (u16*)(ws + 2 * MBYTE);
    u16* WvT  = (u16*)(ws + 4 * MBYTE);
    u16* WoT  = (u16*)(ws + 6 * MBYTE);
    u16* Qws  = (u16*)(ws + 8 * MBYTE);
    u16* Kws  = (u16*)(ws + 16 * MBYTE);
    u16* Vtws = (u16*)(ws + 24 * MBYTE);
    u16* ctxw = (u16*)(ws + 32 * MBYTE);
    int* flags = (int*)(ws + 40 * MBYTE);
    u16* linv_g = (u16*)(ws + 40 * MBYTE + 16);   // 8KB

    u16* relT = (u16*)d_out;   // 8KB scratch in out-region; overwritten by final gemm

    sniffrelk<<<dim3(1), 256, 0, stream>>>((const u32*)query, (const u32*)mask, rel, relT, flags);
    tposek<<<dim3(16, 16, 4), 256, 0, stream>>>(Wq, Wk, Wv, Wo, WqT, WkT, WvT, WoT, flags);
    gemm128<<<dim3(768), 512, 0, stream>>>(query, key, value, WqT, WkT, WvT,
                                           bq, bk, bv, Qws, Kws, Vtws, 0, flags, 1,
                                           768, d_out, linv_g);
    attnk<<<dim3(1024), 256, 0, stream>>>(Qws, Kws, Vtws, rel, relT, mask,
                                          ctxw, d_out, linv_g, flags);
    // final gemm (256 blocks) + piggybacked attn rescale (128 blocks)
    gemm128<<<dim3(384), 512, 0, stream>>>(ctxw, ctxw, ctxw, WoT, WoT, WoT,
                                           bo, bo, bo, d_out, d_out, d_out, 3, flags, 0,
                                           256, d_out, linv_g);
}